// Round 6
// baseline (178.724 us; speedup 1.0000x reference)
//
#include <hip/hip_runtime.h>
#include <math.h>

#define B_  2
#define N_  50
#define n_  15
#define C_  17
#define HW_ 4096
#define KC  32
#define CHB 2176          // chunks per batch element: C_ * (HW_/KC)
#define PSTR 52           // pred LDS row stride (floats); float4 staging measured 0 conflicts (r2)
#define GSTR 20           // gt LDS row stride
#define MASK_OFF 0        // 510 floats: mask per (b,j,c)
#define NKP_OFF 512       // 30 floats: num_kp per (b,j)
#define FLAG_OFF 576      // uints: per-region nonzero flags, 2*nreg <= 1088 -> [576,1664)
#define REG_OFF 4096      // float offset of partial regions
#define RSZ 832           // region: 52 i-rows x 16 j
#define NOUT (B_*N_*n_)   // 1500

__device__ __forceinline__ void pred_feats(float x, float& a1, float& a2, float& b1) {
    float e  = __expf(-fabsf(x));
    float L  = __logf(1.f + e);                  // log1p(e), e in (0,1]
    float r  = __builtin_amdgcn_rcpf(1.f + e);
    float p  = (x >= 0.f) ? r : e * r;           // sigmoid(x)
    float sp = fmaxf(x, 0.f) + L;                // softplus(x)
    float p2 = p * p;
    a1 = sp * p2;
    a2 = -x * p2;
    float om = 1.f - p;
    b1 = (sp - x) * om * om;
}

// ---------------- kernel 1: hm feature GEMM + per-region gt-nonzero flags ----------------
// Partials are UNSCALED (mask * 2/num_kp applied in reduce_kernel) so no mask dependency here.
#define FMA4(acc, a, u) \
    acc.x = fmaf(a, u.x, acc.x); acc.y = fmaf(a, u.y, acc.y); \
    acc.z = fmaf(a, u.z, acc.z); acc.w = fmaf(a, u.w, acc.w);

// smem: 6912 floats = 27648 B -> 5 blocks/CU
__global__ __launch_bounds__(256) void hm_kernel(const float* __restrict__ ph,
                                                 const float* __restrict__ gh,
                                                 float* __restrict__ ws,
                                                 int cpb, int nreg) {
    __shared__ __align__(16) float smem[3 * KC * PSTR + 3 * KC * GSTR];
    __shared__ unsigned s_flags;
    float* sA1 = smem;
    float* sA2 = smem + KC * PSTR;
    float* sB1 = smem + 2 * KC * PSTR;
    float* sU  = smem + 3 * KC * PSTR;
    float* sV  = sU + KC * GSTR;
    float* sW  = sU + 2 * KC * GSTR;

    int rg = blockIdx.x, b = blockIdx.y;
    int tid = threadIdx.x;
    int w = tid >> 6, lane = tid & 63;
    int it = lane % 13, jt = lane / 13;
    bool active = lane < 52;
    int kk = tid & 31, slot = tid >> 5;   // staging roles: 32 k-lanes x 8 slots

    // prefetch registers: raw globals for one chunk
    float rgt[4];   // gt, slot<4 only
    float rph[8];   // pred, 2 i-quads (1 for slot>=5)

    auto issue = [&](int cc) {            // issue global loads for chunk cc
        int ci = rg * cpb + cc;
        int c  = ci >> 7;                 // 128 chunks per c
        int k0 = (ci & 127) * KC;
        if (slot < 4) {
            for (int s = 0; s < 4; ++s) {
                int j = 4 * slot + s;
                rgt[s] = (j < n_) ? gh[(((size_t)(b * n_ + j)) * C_ + c) * HW_ + k0 + kk] : 0.f;
            }
        }
        int qi = 0;
        for (int q = slot; q < 13; q += 8, ++qi)
            for (int s = 0; s < 4; ++s) {
                int i = 4 * q + s;
                rph[4 * qi + s] = (i < N_) ? ph[(((size_t)(b * N_ + i)) * C_ + c) * HW_ + k0 + kk] : 0.f;
            }
    };

    issue(0);
    if (tid == 0) s_flags = 0u;
    __syncthreads();

    float4 acc0 = make_float4(0.f, 0.f, 0.f, 0.f);
    float4 acc1 = acc0, acc2 = acc0, acc3 = acc0;

    for (int cc = 0; cc < cpb; ++cc) {
        // ---- feats from prefetched regs -> LDS (compiler inserts the vmcnt wait here) ----
        if (slot < 4) {
            unsigned bits = 0;
            float uq[4], vq[4], wq[4];
            for (int s = 0; s < 4; ++s) {
                float t = rgt[s];
                if (t != 0.f) bits |= 1u << (4 * slot + s);
                float q1 = 1.f - t, u = q1 * q1; u *= u;
                uq[s] = u;                       // (1-t)^4        (unscaled)
                vq[s] = t * u;                   // t(1-t)^4
                wq[s] = (t == 1.f) ? 1.f : 0.f;  // [t==1]
            }
            if (bits) atomicOr(&s_flags, bits);  // LDS-scope
            *(float4*)&sU[kk * GSTR + 4 * slot] = make_float4(uq[0], uq[1], uq[2], uq[3]);
            *(float4*)&sV[kk * GSTR + 4 * slot] = make_float4(vq[0], vq[1], vq[2], vq[3]);
            *(float4*)&sW[kk * GSTR + 4 * slot] = make_float4(wq[0], wq[1], wq[2], wq[3]);
        }
        {
            int qi = 0;
            for (int q = slot; q < 13; q += 8, ++qi) {
                float a1[4], a2[4], b1[4];
                for (int s = 0; s < 4; ++s) pred_feats(rph[4 * qi + s], a1[s], a2[s], b1[s]);
                *(float4*)&sA1[kk * PSTR + 4 * q] = make_float4(a1[0], a1[1], a1[2], a1[3]);
                *(float4*)&sA2[kk * PSTR + 4 * q] = make_float4(a2[0], a2[1], a2[2], a2[3]);
                *(float4*)&sB1[kk * PSTR + 4 * q] = make_float4(b1[0], b1[1], b1[2], b1[3]);
            }
        }
        if (cc + 1 < cpb) issue(cc + 1);   // prefetch next chunk; in flight across contraction
        __syncthreads();

        // ---- contraction: wave w covers k in [8w,8w+8); lane tile 4i x 4j ----
        if (active) {
#pragma unroll
            for (int k2 = 0; k2 < 8; ++k2) {
                int k = w * 8 + k2;
                float4 a1 = *(const float4*)&sA1[k * PSTR + 4 * it];
                float4 a2 = *(const float4*)&sA2[k * PSTR + 4 * it];
                float4 b1 = *(const float4*)&sB1[k * PSTR + 4 * it];
                float4 u4 = *(const float4*)&sU[k * GSTR + 4 * jt];
                float4 v4 = *(const float4*)&sV[k * GSTR + 4 * jt];
                float4 w4 = *(const float4*)&sW[k * GSTR + 4 * jt];
                FMA4(acc0, a1.x, u4) FMA4(acc0, a2.x, v4) FMA4(acc0, b1.x, w4)
                FMA4(acc1, a1.y, u4) FMA4(acc1, a2.y, v4) FMA4(acc1, b1.y, w4)
                FMA4(acc2, a1.z, u4) FMA4(acc2, a2.z, v4) FMA4(acc2, b1.z, w4)
                FMA4(acc3, a1.w, u4) FMA4(acc3, a2.w, v4) FMA4(acc3, b1.w, w4)
            }
        }
        __syncthreads();   // features consumed; safe to restage
    }

    // ---- dump + fold + coalesced store (layout as r5; known ~679K conflicts ≈ 1 µs, deferred) ----
    float* scratch = smem;
    if (active) {
        float4 accs[4] = {acc0, acc1, acc2, acc3};
        for (int s = 0; s < 4; ++s)
            *(float4*)&scratch[w * RSZ + (4 * it + s) * 16 + 4 * jt] = accs[s];
    }
    __syncthreads();
    float* reg = ws + REG_OFF + ((size_t)(b * nreg + rg)) * RSZ;
    for (int v = tid; v < RSZ; v += 256)
        reg[v] = scratch[v] + scratch[RSZ + v] + scratch[2 * RSZ + v] + scratch[3 * RSZ + v];
    if (tid == 0) ((unsigned*)ws)[FLAG_OFF + b * nreg + rg] = s_flags;
}

// ---------------- kernel 2: fold flags -> mask + num_kp ----------------
__global__ void flagfold_kernel(float* __restrict__ ws, int nreg, int rpc) {
    int t = threadIdx.x;
    if (t >= B_ * n_) return;
    int b = t / n_, j = t % n_;
    const unsigned* flags = (const unsigned*)ws + FLAG_OFF + b * nreg;
    float cnt = 0.f;
    for (int c = 0; c < C_; ++c) {
        unsigned any = 0;
        for (int rr = 0; rr < rpc; ++rr) any |= flags[c * rpc + rr];
        float m = ((any >> j) & 1u) ? 1.f : 0.f;
        ws[MASK_OFF + (b * n_ + j) * C_ + c] = m;
        cnt += m;
    }
    ws[NKP_OFF + b * n_ + j] = fmaxf(cnt, 1.f);
}

// ---------------- kernel 3: score + offset cost (plain stores) ----------------
__global__ void scoreoff_kernel(const float* __restrict__ ps, const float* __restrict__ po,
                                const float* __restrict__ go, const float* __restrict__ ws,
                                float* __restrict__ out) {
    int idx = blockIdx.x * 256 + threadIdx.x;
    if (idx >= NOUT) return;
    int b = idx / (N_ * n_);
    int rem = idx % (N_ * n_);
    int i = rem / n_, j = rem % n_;

    float s  = ps[b * N_ + i];
    float e  = __expf(-fabsf(s));
    float L  = __logf(1.f + e);
    float spn = fmaxf(-s, 0.f) + L;
    float r  = __builtin_amdgcn_rcpf(1.f + e);
    float sig = (s >= 0.f) ? r : e * r;
    float om = 1.f - sig;
    float sc = 0.25f * spn * om * om;

    float off = 0.f;
    const float* nmrow = ws + MASK_OFF + (b * n_ + j) * C_;
    for (int c = 0; c < C_; ++c) {
        float nm = nmrow[c];
        if (nm != 0.f) {
            for (int d = 0; d < 2; ++d) {
                float x = po[((b * N_ + i) * C_ + c) * 2 + d];
                float g = go[((b * n_ + j) * C_ + c) * 2 + d];
                float ee = __expf(-fabsf(x));
                float rr = __builtin_amdgcn_rcpf(1.f + ee);
                float sg = (x >= 0.f) ? rr : ee * rr;
                float dd = sg - g;
                off += dd * dd;
            }
        }
    }
    out[idx] = sc + off / ws[NKP_OFF + b * n_ + j] * 0.5f;
}

// ---------------- kernel 4: fold regions into out, applying mask * 2/num_kp ----------------
__global__ void reduce_kernel(const float* __restrict__ ws, float* __restrict__ out,
                              int nreg, int rpc) {
    int i = blockIdx.x, b = blockIdx.y;
    int t = threadIdx.x;
    int j = t & 15, g = t >> 4;                  // 16 j-lanes x 16 region-groups
    __shared__ float sm[n_][C_];
    __shared__ float sred[16][17];
    if (t < n_ * C_) sm[t / C_][t % C_] = ws[MASK_OFF + (b * n_ + t / C_) * C_ + t % C_];
    __syncthreads();

    const float* base = ws + REG_OFF + ((size_t)b * nreg) * RSZ + i * 16 + j;
    bool ok = j < n_;
    float s = 0.f;
    for (int c = 0; c < C_; ++c) {
        float m = ok ? sm[j][c] : 0.f;
        if (m != 0.f) {
            float ps = 0.f;
            for (int rr = g; rr < rpc; rr += 16)
                ps += base[(size_t)(c * rpc + rr) * RSZ];
            s += m * ps;
        }
    }
    sred[g][j] = s;
    __syncthreads();
    if (g == 0 && ok) {
        float tt = 0.f;
        for (int gg = 0; gg < 16; ++gg) tt += sred[gg][j];
        out[(b * N_ + i) * n_ + j] += tt * 2.f / ws[NKP_OFF + b * n_ + j];
    }
}

extern "C" void kernel_launch(void* const* d_in, const int* in_sizes, int n_in,
                              void* d_out, int out_size, void* d_ws, size_t ws_size,
                              hipStream_t stream) {
    const float* ph = (const float*)d_in[0];
    const float* ps = (const float*)d_in[1];
    const float* po = (const float*)d_in[2];
    const float* gh = (const float*)d_in[3];
    const float* go = (const float*)d_in[4];
    float* out = (float*)d_out;
    float* ws  = (float*)d_ws;

    long availf = (long)(ws_size / 4);
    int cpb = 4;                                  // 544x2 blocks, 3.6 MB regions
    while (cpb < 128 && REG_OFF + 2L * (CHB / cpb) * RSZ > availf) cpb *= 2;
    int nreg = CHB / cpb;                         // regions per batch elem
    int rpc  = 128 / cpb;                         // regions per c

    hm_kernel<<<dim3(nreg, B_), 256, 0, stream>>>(ph, gh, ws, cpb, nreg);
    flagfold_kernel<<<1, 64, 0, stream>>>(ws, nreg, rpc);
    scoreoff_kernel<<<(NOUT + 255) / 256, 256, 0, stream>>>(ps, po, go, ws, out);
    reduce_kernel<<<dim3(N_, B_), 256, 0, stream>>>(ws, out, nreg, rpc);
}

// Round 10
// 143.389 us; speedup vs baseline: 1.2464x; 1.2464x over previous
//
#include <hip/hip_runtime.h>
#include <math.h>

#define B_  2
#define N_  50
#define n_  15
#define C_  17
#define HW_ 4096
#define KC  32
#define CHB 2176          // KC-chunks per batch element: C_ * (HW_/KC)
#define PSTR 52           // pred LDS row stride (floats); contraction reads measured 0 conflicts (r2)
#define GSTR 20           // gt LDS row stride
#define SCR_STR 17        // scratch dump row stride (16 in r5 was a 13-way conflict -> 679K)
#define FLAG_OFF 576      // uint index: per-region flags, B_*nreg <= 2176 -> [576,2752)
#define REG_OFF 4096      // float offset of partial regions
#define RSZ 832           // region: 52 i-rows x 16 j
#define NOUT (B_*N_*n_)   // 1500

__device__ __forceinline__ void pred_feats(float x, float& a1, float& a2, float& b1) {
    float e  = __expf(-fabsf(x));
    float L  = __logf(1.f + e);                  // log1p(e), e in (0,1]
    float r  = __builtin_amdgcn_rcpf(1.f + e);
    float p  = (x >= 0.f) ? r : e * r;           // sigmoid(x)
    float sp = fmaxf(x, 0.f) + L;                // softplus(x)
    float p2 = p * p;
    a1 = sp * p2;
    a2 = -x * p2;
    float om = 1.f - p;
    b1 = (sp - x) * om * om;                     // only used on rare t==1 path
}

// ---------------- kernel 1: hm feature GEMM (unscaled partials) + region flags ----------------
// smem: 2*32*52 + 2*32*20 = 4608 floats = 18.4 KB -> ~8 blocks/CU (was 27.6 KB / 5)
__global__ __launch_bounds__(256) void hm_kernel(const float* __restrict__ ph,
                                                 const float* __restrict__ gh,
                                                 float* __restrict__ ws,
                                                 int cpb, int nreg) {
    __shared__ __align__(16) float smem[2 * KC * PSTR + 2 * KC * GSTR];
    __shared__ unsigned s_flags;        // cumulative t!=0 bits per j (mask input)
    __shared__ unsigned s_hasone[2];    // per-chunk (parity-buffered) "some t==1" flag
    float* sA1 = smem;
    float* sA2 = smem + KC * PSTR;
    float* sU  = smem + 2 * KC * PSTR;
    float* sV  = sU + KC * GSTR;

    int rg = blockIdx.x, b = blockIdx.y;
    int tid = threadIdx.x;
    int w = tid >> 6, lane = tid & 63;
    int it = lane % 13, jt = lane / 13;
    bool active = lane < 52;
    int kk = tid & 31, slot = tid >> 5;   // staging roles: 32 k-lanes x 8 slots

    if (tid == 0) { s_flags = 0u; s_hasone[0] = 0u; s_hasone[1] = 0u; }
    __syncthreads();

    float acc[4][4];
#pragma unroll
    for (int s = 0; s < 4; ++s)
#pragma unroll
        for (int q = 0; q < 4; ++q) acc[s][q] = 0.f;

    int c = 0, k0 = 0;  // live across phases for the rare path
    for (int cc = 0; cc < cpb; ++cc) {
        int ci = rg * cpb + cc;           // cpb divides 128 -> whole block shares c
        c  = ci >> 7;
        k0 = (ci & 127) * KC;

        // ---- stage gt: slots 0..3 own j-quads; load->feats->float4 LDS write ----
        if (slot < 4) {
            unsigned bits = 0, hasone = 0;
            float uq[4], vq[4];
#pragma unroll
            for (int s = 0; s < 4; ++s) {
                int j = 4 * slot + s;
                float t = (j < n_) ? gh[(((size_t)(b * n_ + j)) * C_ + c) * HW_ + k0 + kk] : 0.f;
                if (t != 0.f) bits |= 1u << j;
                if (t == 1.f) hasone = 1u;
                float q1 = 1.f - t, u = q1 * q1; u *= u;
                uq[s] = u;                                   // (1-t)^4
                vq[s] = (t == 1.f) ? -0.0f : t * u;          // t(1-t)^4; -0.0 encodes [t==1]
            }
            if (bits)   atomicOr(&s_flags, bits);            // LDS-scope
            if (hasone) atomicOr(&s_hasone[cc & 1], 1u);
            *(float4*)&sU[kk * GSTR + 4 * slot] = make_float4(uq[0], uq[1], uq[2], uq[3]);
            *(float4*)&sV[kk * GSTR + 4 * slot] = make_float4(vq[0], vq[1], vq[2], vq[3]);
        }
        // ---- stage pred: slot q owns i-quads {q, q+8} (q<5) ----
        for (int q = slot; q < 13; q += 8) {
            float a1[4], a2[4], bu;
#pragma unroll
            for (int s = 0; s < 4; ++s) {
                int i = 4 * q + s;
                float x = (i < N_) ? ph[(((size_t)(b * N_ + i)) * C_ + c) * HW_ + k0 + kk] : 0.f;
                pred_feats(x, a1[s], a2[s], bu);   // bu unused (no b1 staging)
            }
            *(float4*)&sA1[kk * PSTR + 4 * q] = make_float4(a1[0], a1[1], a1[2], a1[3]);
            *(float4*)&sA2[kk * PSTR + 4 * q] = make_float4(a2[0], a2[1], a2[2], a2[3]);
        }
        __syncthreads();

        // ---- contraction: wave w covers k in [8w,8w+8); lane tile 4i x 4j; 4 reads + 32 fma / k ----
        if (active) {
#pragma unroll
            for (int k2 = 0; k2 < 8; ++k2) {
                int k = w * 8 + k2;
                float4 a1 = *(const float4*)&sA1[k * PSTR + 4 * it];
                float4 a2 = *(const float4*)&sA2[k * PSTR + 4 * it];
                float4 u4 = *(const float4*)&sU[k * GSTR + 4 * jt];
                float4 v4 = *(const float4*)&sV[k * GSTR + 4 * jt];
                const float au[4] = {a1.x, a1.y, a1.z, a1.w};
                const float av[4] = {a2.x, a2.y, a2.z, a2.w};
                const float gu[4] = {u4.x, u4.y, u4.z, u4.w};
                const float gv[4] = {v4.x, v4.y, v4.z, v4.w};
#pragma unroll
                for (int s = 0; s < 4; ++s)
#pragma unroll
                    for (int q = 0; q < 4; ++q)
                        acc[s][q] = fmaf(au[s], gu[q], fmaf(av[s], gv[q], acc[s][q]));
            }
        }
        // ---- rare path: some t==1 in this chunk -> add b1 terms (never taken on random data) ----
        if (s_hasone[cc & 1]) {
            if (active) {
                for (int k2 = 0; k2 < 8; ++k2) {
                    int k = w * 8 + k2;
                    float4 v4 = *(const float4*)&sV[k * GSTR + 4 * jt];
                    const float gv[4] = {v4.x, v4.y, v4.z, v4.w};
#pragma unroll
                    for (int q = 0; q < 4; ++q) {
                        if (__float_as_uint(gv[q]) == 0x80000000u) {   // exact -0.0 marker
#pragma unroll
                            for (int s = 0; s < 4; ++s) {
                                int i = 4 * it + s;
                                float x = (i < N_) ? ph[(((size_t)(b * N_ + i)) * C_ + c) * HW_ + k0 + k] : 0.f;
                                float a1r, a2r, b1r;
                                pred_feats(x, a1r, a2r, b1r);
                                acc[s][q] += b1r;
                            }
                        }
                    }
                }
            }
            if (tid == 0) s_hasone[cc & 1] = 0u;   // reset; next same-parity write is 2 barriers away
        }
        __syncthreads();   // features consumed; safe to restage (and orders flag reset)
    }

    // ---- dump to scratch (stride 17), fold, coalesced region store ----
    float* scratch = smem;                     // 4 * 52 * 17 = 3536 <= 4608
    if (active) {
#pragma unroll
        for (int s = 0; s < 4; ++s)
            *(float4*)&scratch[(w * 52 + 4 * it + s) * SCR_STR + 4 * jt] =
                make_float4(acc[s][0], acc[s][1], acc[s][2], acc[s][3]);
    }
    __syncthreads();
    float* reg = ws + REG_OFF + ((size_t)(b * nreg + rg)) * RSZ;
    for (int v = tid; v < RSZ; v += 256) {
        int row = v >> 4, col = v & 15;
        float s = scratch[(row)       * SCR_STR + col]
                + scratch[(52 + row)  * SCR_STR + col]
                + scratch[(104 + row) * SCR_STR + col]
                + scratch[(156 + row) * SCR_STR + col];
        reg[v] = s;
    }
    if (tid == 0) ((unsigned*)ws)[FLAG_OFF + b * nreg + rg] = s_flags;
}

// ---------------- kernel 2: fused mask-fold + region-reduce + score + offset ----------------
__global__ void finish_kernel(const float* __restrict__ ps, const float* __restrict__ po,
                              const float* __restrict__ go, const float* __restrict__ ws,
                              float* __restrict__ out, int nreg, int rpc) {
    int i = blockIdx.x, b = blockIdx.y;
    int t = threadIdx.x;
    __shared__ float sm[n_][C_];      // mask
    __shared__ float snkp[n_];
    __shared__ float sred[16][17];

    // mask from region flags (each region flag covers one (c, rr) slice)
    const unsigned* flags = (const unsigned*)ws + FLAG_OFF + b * nreg;
    if (t < n_ * C_) {
        int j = t / C_, c = t % C_;
        unsigned any = 0;
        for (int rr = 0; rr < rpc; ++rr) any |= flags[c * rpc + rr];
        sm[j][c] = ((any >> j) & 1u) ? 1.f : 0.f;
    }
    __syncthreads();
    if (t < n_) {
        float cnt = 0.f;
        for (int c = 0; c < C_; ++c) cnt += sm[t][c];
        snkp[t] = fmaxf(cnt, 1.f);
    }
    __syncthreads();

    // fold hm regions: 16 j-lanes x 16 region-groups, mask applied per c
    int j = t & 15, g = t >> 4;
    bool ok = j < n_;
    const float* base = ws + REG_OFF + ((size_t)b * nreg) * RSZ + i * 16 + j;
    float s = 0.f;
    for (int c = 0; c < C_; ++c) {
        float m = ok ? sm[j][c] : 0.f;
        if (m != 0.f) {
            float psum = 0.f;
            for (int rr = g; rr < rpc; rr += 16)
                psum += base[(size_t)(c * rpc + rr) * RSZ];
            s += psum;
        }
    }
    sred[g][j] = s;
    __syncthreads();

    if (g == 0 && ok) {
        float hm = 0.f;
        for (int gg = 0; gg < 16; ++gg) hm += sred[gg][j];
        float nkp = snkp[j];

        // score cost
        float sv  = ps[b * N_ + i];
        float e   = __expf(-fabsf(sv));
        float L   = __logf(1.f + e);
        float spn = fmaxf(-sv, 0.f) + L;                  // softplus(-s)
        float r   = __builtin_amdgcn_rcpf(1.f + e);
        float sig = (sv >= 0.f) ? r : e * r;
        float om  = 1.f - sig;
        float sc  = 0.25f * spn * om * om;

        // offset cost
        float off = 0.f;
        for (int c = 0; c < C_; ++c) {
            if (sm[j][c] != 0.f) {
                for (int d = 0; d < 2; ++d) {
                    float x = po[((b * N_ + i) * C_ + c) * 2 + d];
                    float gg = go[((b * n_ + j) * C_ + c) * 2 + d];
                    float ee = __expf(-fabsf(x));
                    float rr = __builtin_amdgcn_rcpf(1.f + ee);
                    float sg = (x >= 0.f) ? rr : ee * rr;
                    float dd = sg - gg;
                    off += dd * dd;
                }
            }
        }
        out[(b * N_ + i) * n_ + j] = hm * 2.f / nkp + sc + off / nkp * 0.5f;
    }
}

extern "C" void kernel_launch(void* const* d_in, const int* in_sizes, int n_in,
                              void* d_out, int out_size, void* d_ws, size_t ws_size,
                              hipStream_t stream) {
    const float* ph = (const float*)d_in[0];
    const float* ps = (const float*)d_in[1];
    const float* po = (const float*)d_in[2];
    const float* gh = (const float*)d_in[3];
    const float* go = (const float*)d_in[4];
    float* out = (float*)d_out;
    float* ws  = (float*)d_ws;

    // cpb=2 default (2176 blocks, 8.5/CU, 7.2 MB regions); escalate if ws is small
    long availf = (long)(ws_size / 4);
    int cpb = 2;
    while (cpb < 128 && REG_OFF + 2L * (CHB / cpb) * RSZ > availf) cpb *= 2;
    int nreg = CHB / cpb;        // regions per batch elem
    int rpc  = 128 / cpb;        // regions per c

    hm_kernel<<<dim3(nreg, B_), 256, 0, stream>>>(ph, gh, ws, cpb, nreg);
    finish_kernel<<<dim3(N_, B_), 256, 0, stream>>>(ps, po, go, ws, out, nreg, rpc);
}